// Round 4
// baseline (644.542 us; speedup 1.0000x reference)
//
#include <hip/hip_runtime.h>

#define L_SEQ 2048
#define D_DIM 768
#define N_ST 16
#define NB 4
#define NJ 33   // 16 B + 16 C + 1 s1
#define NROWS (NB * L_SEQ)          // 8192
#define PROJ_ELEMS (NROWS * NJ)     // 270336
#define NCHAIN (NB * 3)             // 12 independent scan chains

// proj GEMM tiling
#define DSPLIT 8
#define DSEG (D_DIM / DSPLIT)       // 96
#define DK 32
#define NCHUNK (DSEG / DK)          // 3
#define RB 128                      // rows per block
#define XST 132                     // xs_t row stride
#define WST 64                      // ws_t row stride

__device__ __forceinline__ float fast_exp2(float x) {
#if __has_builtin(__builtin_amdgcn_exp2f)
  return __builtin_amdgcn_exp2f(x);
#else
  return __expf(x * 0.69314718055994531f);
#endif
}

__device__ __forceinline__ float softplus_f(float v) {
  float e = __expf(v);
  float l = __logf(1.0f + e);
  return (v > 15.0f) ? v : l;
}

// ---------------------------------------------------------------------------
// Projection GEMM, K-split 8 ways. (Unchanged from round 3 — verified.)
// ---------------------------------------------------------------------------
__global__ __launch_bounds__(256) void k_proj_gemm(
    const float* __restrict__ x, const float* __restrict__ W_bc,
    const float* __restrict__ W_1, float* __restrict__ PBC) {
  __shared__ float xs_t[DK * XST];   // [dk][row]
  __shared__ float ws_t[DK * WST];   // [dk][jslot]

  const int ds  = blockIdx.x % DSPLIT;
  const int rb0 = (blockIdx.x / DSPLIT) * RB;
  const int dbase = ds * DSEG;
  const int tid = threadIdx.x;

  const int rg = tid & 31;
  const int jg = tid >> 5;

  float acc[4][5];
#pragma unroll
  for (int i = 0; i < 4; ++i)
#pragma unroll
    for (int k = 0; k < 5; ++k) acc[i][k] = 0.0f;

  const int lrow = tid >> 1;
  const int lhalf = (tid & 1) * 16;
  const float* xg_row = x + (size_t)(rb0 + lrow) * D_DIM + dbase + lhalf;

  for (int ch = 0; ch < NCHUNK; ++ch) {
    const int dc = dbase + ch * DK;
    float4 xv[4];
#pragma unroll
    for (int q = 0; q < 4; ++q)
      xv[q] = *(const float4*)(xg_row + ch * DK + q * 4);
    float wv[8];
    int widx[8];
#pragma unroll
    for (int u = 0; u < 8; ++u) {
      int idx = tid + u * 256;
      int dk = idx >> 6, slot = idx & 63;
      int wjg = slot >> 3, wk = slot & 7;
      int j = wjg + 8 * wk;
      float v = 0.0f;
      if (wk < 5) {
        if (j < 32)       v = W_bc[(size_t)j * D_DIM + dc + dk];
        else if (j == 32) v = W_1[dc + dk];
      }
      wv[u] = v; widx[u] = dk * WST + slot;
    }
    __syncthreads();
#pragma unroll
    for (int q = 0; q < 4; ++q) {
      xs_t[(lhalf + q * 4 + 0) * XST + lrow] = xv[q].x;
      xs_t[(lhalf + q * 4 + 1) * XST + lrow] = xv[q].y;
      xs_t[(lhalf + q * 4 + 2) * XST + lrow] = xv[q].z;
      xs_t[(lhalf + q * 4 + 3) * XST + lrow] = xv[q].w;
    }
#pragma unroll
    for (int u = 0; u < 8; ++u) ws_t[widx[u]] = wv[u];
    __syncthreads();
#pragma unroll 8
    for (int dk = 0; dk < DK; ++dk) {
      float4 xr = *(const float4*)&xs_t[dk * XST + rg * 4];
      float4 wr = *(const float4*)&ws_t[dk * WST + jg * 8];
      float w4  = ws_t[dk * WST + jg * 8 + 4];
      float xa[4] = {xr.x, xr.y, xr.z, xr.w};
      float wa[5] = {wr.x, wr.y, wr.z, wr.w, w4};
#pragma unroll
      for (int i = 0; i < 4; ++i)
#pragma unroll
        for (int k = 0; k < 5; ++k)
          acc[i][k] = fmaf(xa[i], wa[k], acc[i][k]);
    }
  }

  float* pb = PBC + (size_t)ds * PROJ_ELEMS;
#pragma unroll
  for (int i = 0; i < 4; ++i) {
    int row = rb0 + rg * 4 + i;
#pragma unroll
    for (int k = 0; k < 5; ++k) {
      int j = jg + 8 * k;
      if (k < 4 || jg == 0) pb[(size_t)row * NJ + j] = acc[i][k];
    }
  }
}

__global__ __launch_bounds__(256) void k_proj_reduce(
    const float* __restrict__ PBC, const float* __restrict__ b_bc,
    const float* __restrict__ b_1, float* __restrict__ BC33) {
  const int idx = blockIdx.x * 256 + threadIdx.x;
  const int j = idx % NJ;
  float s = 0.0f;
#pragma unroll
  for (int k = 0; k < DSPLIT; ++k) s += PBC[(size_t)k * PROJ_ELEMS + idx];
  s += (j < 32) ? b_bc[j] : b_1[0];
  BC33[idx] = s;
}

// ---------------------------------------------------------------------------
// Single-pass chunked scan with decoupled lookback.
// Grid: NCHAIN * NC blocks, blockIdx = c*NCHAIN + chain (predecessors have
// strictly smaller blockIdx; all blocks co-resident at 3/CU). Each block:
//   A) local scan (h0=0), y_local -> LDS, aggregate (dsum, h[16]) -> global
//   B) lookback over predecessors' aggregates / inclusive states -> h_in
//   C) publish inclusive h_out; correction y_l += sum_n exp2(Aln*S_l)*h_in*C
// ---------------------------------------------------------------------------
template <int LC>
__global__ __launch_bounds__(256) void k_scan_fused(
    const float* __restrict__ x, const float* __restrict__ A_log,
    const float* __restrict__ W_d, const float* __restrict__ b_d,
    const float* __restrict__ BC33, float* __restrict__ AGG_DS,
    float* __restrict__ AGG_H, float* __restrict__ AGG_HO,
    int* flags, float* __restrict__ out) {
  __shared__ float ylds[LC * 256];
  const int tid = threadIdx.x;
  const int bid = blockIdx.x;
  const int chain = bid % NCHAIN;
  const int c = bid / NCHAIN;
  const int b = chain / 3, cb = chain % 3;
  const int d = cb * 256 + tid;

  const float wd = W_d[d], bd = b_d[d];
  float Aln[N_ST];
#pragma unroll
  for (int n = 0; n < N_ST; ++n)
    Aln[n] = -__expf(A_log[d * N_ST + n]) * 1.44269504088896f;  // A*log2(e)

  float h[N_ST];
#pragma unroll
  for (int n = 0; n < N_ST; ++n) h[n] = 0.0f;
  float dsum = 0.0f;

  const int l0 = c * LC;
  const float* bc = BC33 + (size_t)(b * L_SEQ + l0) * NJ;
  const float* xp = x + (size_t)(b * L_SEQ + l0) * D_DIM + d;

  // ---- phase A: local scan ----
#pragma unroll 8
  for (int l = 0; l < LC; ++l) {
    float s1 = bc[l * NJ + 32];                  // wave-uniform -> s_load
    float delta = softplus_f(fmaf(s1, wd, bd));
    float xv = xp[(size_t)l * D_DIM];
    float f = delta * xv;
    dsum += delta;
    float y = 0.0f;
#pragma unroll
    for (int n = 0; n < N_ST; ++n) {
      float dA = fast_exp2(delta * Aln[n]);
      h[n] = fmaf(dA, h[n], f * bc[l * NJ + n]);
      y = fmaf(h[n], bc[l * NJ + 16 + n], y);
    }
    ylds[l * 256 + tid] = y;
  }

  // ---- publish aggregate ----
  const size_t pme = (size_t)bid * 256 + tid;
  AGG_DS[pme] = dsum;
  {
    float4* Hme = (float4*)(AGG_H + pme * N_ST);
#pragma unroll
    for (int q = 0; q < 4; ++q)
      Hme[q] = make_float4(h[4*q], h[4*q+1], h[4*q+2], h[4*q+3]);
  }
  __threadfence();
  __syncthreads();
  if (tid == 0)
    __hip_atomic_store(flags + bid, 1, __ATOMIC_RELEASE, __HIP_MEMORY_SCOPE_AGENT);

  // ---- phase B: lookback ----
  float hin[N_ST];
#pragma unroll
  for (int n = 0; n < N_ST; ++n) hin[n] = 0.0f;
  if (c > 0) {
    float Hacc[N_ST];
#pragma unroll
    for (int n = 0; n < N_ST; ++n) Hacc[n] = 0.0f;
    float dsacc = 0.0f;
    int j = bid - NCHAIN;
    for (;;) {
      int f;
      do {
        f = __hip_atomic_load(flags + j, __ATOMIC_ACQUIRE, __HIP_MEMORY_SCOPE_AGENT);
        if (f == 0) __builtin_amdgcn_s_sleep(2);
      } while (f == 0);
      const size_t pj = (size_t)j * 256 + tid;
      if (f == 2) {
        const float4* HO4 = (const float4*)(AGG_HO + pj * N_ST);
        float ho[N_ST];
#pragma unroll
        for (int q = 0; q < 4; ++q) {
          float4 v = HO4[q];
          ho[4*q] = v.x; ho[4*q+1] = v.y; ho[4*q+2] = v.z; ho[4*q+3] = v.w;
        }
#pragma unroll
        for (int n = 0; n < N_ST; ++n)
          hin[n] = fmaf(fast_exp2(Aln[n] * dsacc), ho[n], Hacc[n]);
        break;
      } else {
        float dsj = AGG_DS[pj];
        const float4* HJ4 = (const float4*)(AGG_H + pj * N_ST);
        float hj[N_ST];
#pragma unroll
        for (int q = 0; q < 4; ++q) {
          float4 v = HJ4[q];
          hj[4*q] = v.x; hj[4*q+1] = v.y; hj[4*q+2] = v.z; hj[4*q+3] = v.w;
        }
#pragma unroll
        for (int n = 0; n < N_ST; ++n)
          Hacc[n] = fmaf(fast_exp2(Aln[n] * dsacc), hj[n], Hacc[n]);
        dsacc += dsj;
        if (j < NCHAIN) {                        // that chunk was c==0: done
#pragma unroll
          for (int n = 0; n < N_ST; ++n) hin[n] = Hacc[n];
          break;
        }
        j -= NCHAIN;
      }
    }
  }

  // ---- publish inclusive state ----
  {
    float ho[N_ST];
#pragma unroll
    for (int n = 0; n < N_ST; ++n)
      ho[n] = fmaf(fast_exp2(Aln[n] * dsum), hin[n], h[n]);
    float4* HOme = (float4*)(AGG_HO + pme * N_ST);
#pragma unroll
    for (int q = 0; q < 4; ++q)
      HOme[q] = make_float4(ho[4*q], ho[4*q+1], ho[4*q+2], ho[4*q+3]);
  }
  __threadfence();
  __syncthreads();
  if (tid == 0)
    __hip_atomic_store(flags + bid, 2, __ATOMIC_RELEASE, __HIP_MEMORY_SCOPE_AGENT);

  // ---- phase C: correction + output ----
  float* op = out + (size_t)(b * L_SEQ + l0) * D_DIM + d;
  if (c == 0) {
#pragma unroll 8
    for (int l = 0; l < LC; ++l)
      op[(size_t)l * D_DIM] = ylds[l * 256 + tid];
  } else {
    float S = 0.0f;
#pragma unroll 4
    for (int l = 0; l < LC; ++l) {
      float s1 = bc[l * NJ + 32];
      float delta = softplus_f(fmaf(s1, wd, bd));
      S += delta;
      float corr = 0.0f;
#pragma unroll
      for (int n = 0; n < N_ST; ++n)
        corr = fmaf(fast_exp2(Aln[n] * S) * hin[n], bc[l * NJ + 16 + n], corr);
      op[(size_t)l * D_DIM] = ylds[l * 256 + tid] + corr;
    }
  }
}

// ---------------------------------------------------------------------------
extern "C" void kernel_launch(void* const* d_in, const int* in_sizes, int n_in,
                              void* d_out, int out_size, void* d_ws, size_t ws_size,
                              hipStream_t stream) {
  const float* x     = (const float*)d_in[0];
  const float* A_log = (const float*)d_in[1];
  const float* W_bc  = (const float*)d_in[2];
  const float* b_bc  = (const float*)d_in[3];
  const float* W_1   = (const float*)d_in[4];
  const float* b_1   = (const float*)d_in[5];
  const float* W_d   = (const float*)d_in[6];
  const float* b_d   = (const float*)d_in[7];
  float* out = (float*)d_out;
  float* ws  = (float*)d_ws;

  // NC selection: primary NC=64 (LC=32), fallback NC=32 (LC=64)
  int NC = 64;
  {
    size_t need = (9ull * PROJ_ELEMS +
                   (size_t)NCHAIN * 64 * 256 * (1 + 16 + 16) +
                   (size_t)NCHAIN * 64) * 4ull;
    if (ws_size < need) NC = 32;
  }
  const int nblk = NCHAIN * NC;
  const size_t agg_cols = (size_t)nblk * 256;

  float* BC33   = ws;
  float* PBC    = BC33 + PROJ_ELEMS;
  float* AGG_DS = PBC + (size_t)DSPLIT * PROJ_ELEMS;
  float* AGG_H  = AGG_DS + agg_cols;
  float* AGG_HO = AGG_H + agg_cols * N_ST;
  int*   flags  = (int*)(AGG_HO + agg_cols * N_ST);

  hipMemsetAsync(flags, 0, (size_t)nblk * sizeof(int), stream);
  k_proj_gemm<<<(NROWS / RB) * DSPLIT, 256, 0, stream>>>(x, W_bc, W_1, PBC);
  k_proj_reduce<<<PROJ_ELEMS / 256, 256, 0, stream>>>(PBC, b_bc, b_1, BC33);

  if (NC == 64) {
    k_scan_fused<32><<<nblk, 256, 0, stream>>>(
        x, A_log, W_d, b_d, BC33, AGG_DS, AGG_H, AGG_HO, flags, out);
  } else {
    k_scan_fused<64><<<nblk, 256, 0, stream>>>(
        x, A_log, W_d, b_d, BC33, AGG_DS, AGG_H, AGG_HO, flags, out);
  }
}

// Round 5
// 173.867 us; speedup vs baseline: 3.7071x; 3.7071x over previous
//
#include <hip/hip_runtime.h>

#define L_SEQ 2048
#define D_DIM 768
#define N_ST 16
#define NB 4
#define NJ 33   // 16 B + 16 C + 1 s1
#define NROWS (NB * L_SEQ)          // 8192
#define PROJ_ELEMS (NROWS * NJ)     // 270336

// proj GEMM tiling
#define DSPLIT 8
#define DSEG (D_DIM / DSPLIT)       // 96
#define DK 32
#define NCHUNK (DSEG / DK)          // 3
#define RB 128                      // rows per block
#define XST 132                     // xs_t row stride
#define WST 64                      // ws_t row stride

__device__ __forceinline__ float fast_exp2(float x) {
#if __has_builtin(__builtin_amdgcn_exp2f)
  return __builtin_amdgcn_exp2f(x);
#else
  return __expf(x * 0.69314718055994531f);
#endif
}

__device__ __forceinline__ float softplus_f(float v) {
  float e = __expf(v);
  float l = __logf(1.0f + e);
  return (v > 15.0f) ? v : l;
}

// pw[n] = e1^(n+1), log-depth product tree (no fp reassociation needed)
__device__ __forceinline__ void pow_tree(float e1, float pw[N_ST]) {
  pw[0] = e1;
  pw[1] = pw[0] * pw[0];
  pw[2] = pw[1] * pw[0];
  pw[3] = pw[1] * pw[1];
  pw[4] = pw[3] * pw[0];
  pw[5] = pw[3] * pw[1];
  pw[6] = pw[3] * pw[2];
  pw[7] = pw[3] * pw[3];
  pw[8] = pw[7] * pw[0];
  pw[9] = pw[7] * pw[1];
  pw[10] = pw[7] * pw[2];
  pw[11] = pw[7] * pw[3];
  pw[12] = pw[7] * pw[4];
  pw[13] = pw[7] * pw[5];
  pw[14] = pw[7] * pw[6];
  pw[15] = pw[7] * pw[7];
}

// ---------------------------------------------------------------------------
// Projection GEMM, K-split 8 ways. (Verified round 3.)
// ---------------------------------------------------------------------------
__global__ __launch_bounds__(256) void k_proj_gemm(
    const float* __restrict__ x, const float* __restrict__ W_bc,
    const float* __restrict__ W_1, float* __restrict__ PBC) {
  __shared__ float xs_t[DK * XST];   // [dk][row]
  __shared__ float ws_t[DK * WST];   // [dk][jslot]

  const int ds  = blockIdx.x % DSPLIT;
  const int rb0 = (blockIdx.x / DSPLIT) * RB;
  const int dbase = ds * DSEG;
  const int tid = threadIdx.x;

  const int rg = tid & 31;
  const int jg = tid >> 5;

  float acc[4][5];
#pragma unroll
  for (int i = 0; i < 4; ++i)
#pragma unroll
    for (int k = 0; k < 5; ++k) acc[i][k] = 0.0f;

  const int lrow = tid >> 1;
  const int lhalf = (tid & 1) * 16;
  const float* xg_row = x + (size_t)(rb0 + lrow) * D_DIM + dbase + lhalf;

  for (int ch = 0; ch < NCHUNK; ++ch) {
    const int dc = dbase + ch * DK;
    float4 xv[4];
#pragma unroll
    for (int q = 0; q < 4; ++q)
      xv[q] = *(const float4*)(xg_row + ch * DK + q * 4);
    float wv[8];
    int widx[8];
#pragma unroll
    for (int u = 0; u < 8; ++u) {
      int idx = tid + u * 256;
      int dk = idx >> 6, slot = idx & 63;
      int wjg = slot >> 3, wk = slot & 7;
      int j = wjg + 8 * wk;
      float v = 0.0f;
      if (wk < 5) {
        if (j < 32)       v = W_bc[(size_t)j * D_DIM + dc + dk];
        else if (j == 32) v = W_1[dc + dk];
      }
      wv[u] = v; widx[u] = dk * WST + slot;
    }
    __syncthreads();
#pragma unroll
    for (int q = 0; q < 4; ++q) {
      xs_t[(lhalf + q * 4 + 0) * XST + lrow] = xv[q].x;
      xs_t[(lhalf + q * 4 + 1) * XST + lrow] = xv[q].y;
      xs_t[(lhalf + q * 4 + 2) * XST + lrow] = xv[q].z;
      xs_t[(lhalf + q * 4 + 3) * XST + lrow] = xv[q].w;
    }
#pragma unroll
    for (int u = 0; u < 8; ++u) ws_t[widx[u]] = wv[u];
    __syncthreads();
#pragma unroll 8
    for (int dk = 0; dk < DK; ++dk) {
      float4 xr = *(const float4*)&xs_t[dk * XST + rg * 4];
      float4 wr = *(const float4*)&ws_t[dk * WST + jg * 8];
      float w4  = ws_t[dk * WST + jg * 8 + 4];
      float xa[4] = {xr.x, xr.y, xr.z, xr.w};
      float wa[5] = {wr.x, wr.y, wr.z, wr.w, w4};
#pragma unroll
      for (int i = 0; i < 4; ++i)
#pragma unroll
        for (int k = 0; k < 5; ++k)
          acc[i][k] = fmaf(xa[i], wa[k], acc[i][k]);
    }
  }

  float* pb = PBC + (size_t)ds * PROJ_ELEMS;
#pragma unroll
  for (int i = 0; i < 4; ++i) {
    int row = rb0 + rg * 4 + i;
#pragma unroll
    for (int k = 0; k < 5; ++k) {
      int j = jg + 8 * k;
      if (k < 4 || jg == 0) pb[(size_t)row * NJ + j] = acc[i][k];
    }
  }
}

__global__ __launch_bounds__(256) void k_proj_reduce(
    const float* __restrict__ PBC, const float* __restrict__ b_bc,
    const float* __restrict__ b_1, float* __restrict__ BC33) {
  const int idx = blockIdx.x * 256 + threadIdx.x;
  const int j = idx % NJ;
  float s = 0.0f;
#pragma unroll
  for (int k = 0; k < DSPLIT; ++k) s += PBC[(size_t)k * PROJ_ELEMS + idx];
  s += (j < 32) ? b_bc[j] : b_1[0];
  BC33[idx] = s;
}

// ---------------------------------------------------------------------------
// Pass 1: per-chunk local scan, h0 = 0. Emits chunk-end state H and delta-sum
// DS. Geometric-A fast path: dA_n = e1^(n+1), 1 exp + 15 muls per step.
// ---------------------------------------------------------------------------
template <int LC>
__global__ __launch_bounds__(256) void k_scan1(
    const float* __restrict__ x, const float* __restrict__ A_log,
    const float* __restrict__ W_d, const float* __restrict__ b_d,
    const float* __restrict__ BC33, float* __restrict__ DS,
    float* __restrict__ H, int NC) {
  const int cb = blockIdx.x % 3;
  const int c  = (blockIdx.x / 3) % NC;
  const int b  = blockIdx.x / (3 * NC);
  const int d  = cb * 256 + threadIdx.x;

  const float wd = W_d[d], bd = b_d[d];
  float Aln[N_ST];
#pragma unroll
  for (int n = 0; n < N_ST; ++n)
    Aln[n] = -__expf(A_log[d * N_ST + n]) * 1.44269504088896f;  // A * log2(e)

  // geometric structure detection: Aln[n] == (n+1)*Aln[0] ?
  bool geom = true;
#pragma unroll
  for (int n = 1; n < N_ST; ++n) {
    float ref = (float)(n + 1) * Aln[0];
    geom = geom && (fabsf(Aln[n] - ref) <= 1e-4f * fabsf(ref) + 1e-12f);
  }
  const float a0 = Aln[0];

  float h[N_ST];
#pragma unroll
  for (int n = 0; n < N_ST; ++n) h[n] = 0.0f;
  float dsum = 0.0f;

  const int l0 = c * LC;
  const float* bc = BC33 + (size_t)(b * L_SEQ + l0) * NJ;
  const float* xp = x + (size_t)(b * L_SEQ + l0) * D_DIM + d;

  if (geom) {
#pragma unroll 8
    for (int l = 0; l < LC; ++l) {
      float s1 = bc[l * NJ + 32];
      float delta = softplus_f(fmaf(s1, wd, bd));
      float xv = xp[(size_t)l * D_DIM];
      float f = delta * xv;
      dsum += delta;
      float pw[N_ST];
      pow_tree(fast_exp2(a0 * delta), pw);
#pragma unroll
      for (int n = 0; n < N_ST; ++n)
        h[n] = fmaf(pw[n], h[n], f * bc[l * NJ + n]);
    }
  } else {
#pragma unroll 4
    for (int l = 0; l < LC; ++l) {
      float s1 = bc[l * NJ + 32];
      float delta = softplus_f(fmaf(s1, wd, bd));
      float xv = xp[(size_t)l * D_DIM];
      float f = delta * xv;
      dsum += delta;
#pragma unroll
      for (int n = 0; n < N_ST; ++n) {
        float dA = fast_exp2(delta * Aln[n]);
        h[n] = fmaf(dA, h[n], f * bc[l * NJ + n]);
      }
    }
  }

  DS[((size_t)b * NC + c) * D_DIM + d] = dsum;
  size_t base = ((size_t)(b * NC + c) * D_DIM + d) * N_ST;
  float4* H4 = (float4*)(H + base);
#pragma unroll
  for (int q = 0; q < 4; ++q)
    H4[q] = make_float4(h[4*q], h[4*q+1], h[4*q+2], h[4*q+3]);
}

// ---------------------------------------------------------------------------
// Pass 2: inter-chunk combine, in-place: H[c] becomes the INCOMING state.
// ---------------------------------------------------------------------------
__global__ __launch_bounds__(256) void k_combine(
    const float* __restrict__ A_log, const float* __restrict__ DS,
    float* __restrict__ H, int NC) {
  const int b  = blockIdx.x / 48;
  const int tl = (blockIdx.x % 48) * 256 + threadIdx.x;   // 0..12287
  const int d = tl >> 4, n = tl & 15;
  const float Aln = -__expf(A_log[d * N_ST + n]) * 1.44269504088896f;

  const float* dsp = DS + (size_t)b * NC * D_DIM + d;
  float* Hp = H + (size_t)b * NC * (D_DIM * N_ST) + tl;

  float h = 0.0f;
  float ds_c = dsp[0];
  float hold = Hp[0];
#pragma unroll 4
  for (int c = 0; c < NC; ++c) {
    float ds_n = 0.0f, hold_n = 0.0f;
    if (c + 1 < NC) {
      ds_n   = dsp[(size_t)(c + 1) * D_DIM];
      hold_n = Hp[(size_t)(c + 1) * (D_DIM * N_ST)];
    }
    float p = fast_exp2(Aln * ds_c);
    Hp[(size_t)c * (D_DIM * N_ST)] = h;
    h = fmaf(p, h, hold);
    ds_c = ds_n; hold = hold_n;
  }
}

// ---------------------------------------------------------------------------
// Pass 3: re-run the scan from the incoming state, emit y. Geometric fast
// path as in pass 1.
// ---------------------------------------------------------------------------
template <int LC>
__global__ __launch_bounds__(256) void k_scan2(
    const float* __restrict__ x, const float* __restrict__ A_log,
    const float* __restrict__ W_d, const float* __restrict__ b_d,
    const float* __restrict__ BC33, const float* __restrict__ HIN,
    float* __restrict__ out, int NC) {
  const int cb = blockIdx.x % 3;
  const int c  = (blockIdx.x / 3) % NC;
  const int b  = blockIdx.x / (3 * NC);
  const int d  = cb * 256 + threadIdx.x;

  const float wd = W_d[d], bd = b_d[d];
  float Aln[N_ST];
#pragma unroll
  for (int n = 0; n < N_ST; ++n)
    Aln[n] = -__expf(A_log[d * N_ST + n]) * 1.44269504088896f;

  bool geom = true;
#pragma unroll
  for (int n = 1; n < N_ST; ++n) {
    float ref = (float)(n + 1) * Aln[0];
    geom = geom && (fabsf(Aln[n] - ref) <= 1e-4f * fabsf(ref) + 1e-12f);
  }
  const float a0 = Aln[0];

  float h[N_ST];
  size_t base = ((size_t)(b * NC + c) * D_DIM + d) * N_ST;
  const float4* HIN4 = (const float4*)(HIN + base);
#pragma unroll
  for (int q = 0; q < 4; ++q) {
    float4 v = HIN4[q];
    h[4*q] = v.x; h[4*q+1] = v.y; h[4*q+2] = v.z; h[4*q+3] = v.w;
  }

  const int l0 = c * LC;
  const float* bc = BC33 + (size_t)(b * L_SEQ + l0) * NJ;
  const float* xp = x + (size_t)(b * L_SEQ + l0) * D_DIM + d;
  float* op = out + (size_t)(b * L_SEQ + l0) * D_DIM + d;

  if (geom) {
#pragma unroll 8
    for (int l = 0; l < LC; ++l) {
      float s1 = bc[l * NJ + 32];
      float delta = softplus_f(fmaf(s1, wd, bd));
      float xv = xp[(size_t)l * D_DIM];
      float f = delta * xv;
      float pw[N_ST];
      pow_tree(fast_exp2(a0 * delta), pw);
      float y = 0.0f;
#pragma unroll
      for (int n = 0; n < N_ST; ++n) {
        h[n] = fmaf(pw[n], h[n], f * bc[l * NJ + n]);
        y = fmaf(h[n], bc[l * NJ + 16 + n], y);
      }
      op[(size_t)l * D_DIM] = y;
    }
  } else {
#pragma unroll 4
    for (int l = 0; l < LC; ++l) {
      float s1 = bc[l * NJ + 32];
      float delta = softplus_f(fmaf(s1, wd, bd));
      float xv = xp[(size_t)l * D_DIM];
      float f = delta * xv;
      float y = 0.0f;
#pragma unroll
      for (int n = 0; n < N_ST; ++n) {
        float dA = fast_exp2(delta * Aln[n]);
        h[n] = fmaf(dA, h[n], f * bc[l * NJ + n]);
        y = fmaf(h[n], bc[l * NJ + 16 + n], y);
      }
      op[(size_t)l * D_DIM] = y;
    }
  }
}

// ---------------------------------------------------------------------------
extern "C" void kernel_launch(void* const* d_in, const int* in_sizes, int n_in,
                              void* d_out, int out_size, void* d_ws, size_t ws_size,
                              hipStream_t stream) {
  const float* x     = (const float*)d_in[0];
  const float* A_log = (const float*)d_in[1];
  const float* W_bc  = (const float*)d_in[2];
  const float* b_bc  = (const float*)d_in[3];
  const float* W_1   = (const float*)d_in[4];
  const float* b_1   = (const float*)d_in[5];
  const float* W_d   = (const float*)d_in[6];
  const float* b_d   = (const float*)d_in[7];
  float* out = (float*)d_out;
  float* ws  = (float*)d_ws;

  // workspace (floats): BC33 270336 + PBC 8*270336 + DS 3072*NC + H 49152*NC
  int NC = 8;
  const int cands[4] = {128, 64, 32, 16};
  for (int i = 0; i < 4; ++i) {
    size_t need = (9ull * PROJ_ELEMS + (3072ull + 49152ull) * cands[i]) * 4ull;
    if (ws_size >= need) { NC = cands[i]; break; }
  }

  float* BC33 = ws;
  float* PBC  = ws + PROJ_ELEMS;
  float* DSb  = PBC + (size_t)DSPLIT * PROJ_ELEMS;
  float* H    = DSb + (size_t)3072 * NC;

  k_proj_gemm<<<(NROWS / RB) * DSPLIT, 256, 0, stream>>>(x, W_bc, W_1, PBC);
  k_proj_reduce<<<PROJ_ELEMS / 256, 256, 0, stream>>>(PBC, b_bc, b_1, BC33);

  const int gs = 3 * NB * NC;
  switch (NC) {
    case 128:
      k_scan1<16><<<gs, 256, 0, stream>>>(x, A_log, W_d, b_d, BC33, DSb, H, NC);
      k_combine<<<192, 256, 0, stream>>>(A_log, DSb, H, NC);
      k_scan2<16><<<gs, 256, 0, stream>>>(x, A_log, W_d, b_d, BC33, H, out, NC);
      break;
    case 64:
      k_scan1<32><<<gs, 256, 0, stream>>>(x, A_log, W_d, b_d, BC33, DSb, H, NC);
      k_combine<<<192, 256, 0, stream>>>(A_log, DSb, H, NC);
      k_scan2<32><<<gs, 256, 0, stream>>>(x, A_log, W_d, b_d, BC33, H, out, NC);
      break;
    case 32:
      k_scan1<64><<<gs, 256, 0, stream>>>(x, A_log, W_d, b_d, BC33, DSb, H, NC);
      k_combine<<<192, 256, 0, stream>>>(A_log, DSb, H, NC);
      k_scan2<64><<<gs, 256, 0, stream>>>(x, A_log, W_d, b_d, BC33, H, out, NC);
      break;
    case 16:
      k_scan1<128><<<gs, 256, 0, stream>>>(x, A_log, W_d, b_d, BC33, DSb, H, NC);
      k_combine<<<192, 256, 0, stream>>>(A_log, DSb, H, NC);
      k_scan2<128><<<gs, 256, 0, stream>>>(x, A_log, W_d, b_d, BC33, H, out, NC);
      break;
    default:
      k_scan1<256><<<gs, 256, 0, stream>>>(x, A_log, W_d, b_d, BC33, DSb, H, NC);
      k_combine<<<192, 256, 0, stream>>>(A_log, DSb, H, NC);
      k_scan2<256><<<gs, 256, 0, stream>>>(x, A_log, W_d, b_d, BC33, H, out, NC);
      break;
  }
}

// Round 6
// 170.446 us; speedup vs baseline: 3.7815x; 1.0201x over previous
//
#include <hip/hip_runtime.h>

#define L_SEQ 2048
#define D_DIM 768
#define N_ST 16
#define NB 4
#define NJ 33   // 16 B + 16 C + 1 s1
#define NROWS (NB * L_SEQ)          // 8192
#define PROJ_ELEMS (NROWS * NJ)     // 270336

// proj GEMM tiling
#define DSPLIT 8
#define DSEG (D_DIM / DSPLIT)       // 96
#define DK 32
#define NCHUNK (DSEG / DK)          // 3
#define RB 128                      // rows per block
#define XST 132                     // xs_t row stride
#define WST 64                      // ws_t row stride

__device__ __forceinline__ float fast_exp2(float x) {
#if __has_builtin(__builtin_amdgcn_exp2f)
  return __builtin_amdgcn_exp2f(x);
#else
  return __expf(x * 0.69314718055994531f);
#endif
}

// softplus = ln(1+e^v) = log2(1+2^(v*log2e))*ln2 — 2 raw transcendentals,
// no ocml range-reduction. Guard v>15 (exp2 overflow -> inf -> log2(inf)=inf).
__device__ __forceinline__ float softplus_f(float v) {
  float e = fast_exp2(v * 1.44269504088896f);
  float l = __log2f(1.0f + e) * 0.69314718055994531f;
  return (v > 15.0f) ? v : l;
}

// pw[n] = e1^(n+1), log-depth product tree
__device__ __forceinline__ void pow_tree(float e1, float pw[N_ST]) {
  pw[0] = e1;
  pw[1] = pw[0] * pw[0];
  pw[2] = pw[1] * pw[0];
  pw[3] = pw[1] * pw[1];
  pw[4] = pw[3] * pw[0];
  pw[5] = pw[3] * pw[1];
  pw[6] = pw[3] * pw[2];
  pw[7] = pw[3] * pw[3];
  pw[8] = pw[7] * pw[0];
  pw[9] = pw[7] * pw[1];
  pw[10] = pw[7] * pw[2];
  pw[11] = pw[7] * pw[3];
  pw[12] = pw[7] * pw[4];
  pw[13] = pw[7] * pw[5];
  pw[14] = pw[7] * pw[6];
  pw[15] = pw[7] * pw[7];
}

// ---------------------------------------------------------------------------
// Projection GEMM, K-split 8 ways. (Verified round 3.)
// ---------------------------------------------------------------------------
__global__ __launch_bounds__(256) void k_proj_gemm(
    const float* __restrict__ x, const float* __restrict__ W_bc,
    const float* __restrict__ W_1, float* __restrict__ PBC) {
  __shared__ float xs_t[DK * XST];   // [dk][row]
  __shared__ float ws_t[DK * WST];   // [dk][jslot]

  const int ds  = blockIdx.x % DSPLIT;
  const int rb0 = (blockIdx.x / DSPLIT) * RB;
  const int dbase = ds * DSEG;
  const int tid = threadIdx.x;

  const int rg = tid & 31;
  const int jg = tid >> 5;

  float acc[4][5];
#pragma unroll
  for (int i = 0; i < 4; ++i)
#pragma unroll
    for (int k = 0; k < 5; ++k) acc[i][k] = 0.0f;

  const int lrow = tid >> 1;
  const int lhalf = (tid & 1) * 16;
  const float* xg_row = x + (size_t)(rb0 + lrow) * D_DIM + dbase + lhalf;

  for (int ch = 0; ch < NCHUNK; ++ch) {
    const int dc = dbase + ch * DK;
    float4 xv[4];
#pragma unroll
    for (int q = 0; q < 4; ++q)
      xv[q] = *(const float4*)(xg_row + ch * DK + q * 4);
    float wv[8];
    int widx[8];
#pragma unroll
    for (int u = 0; u < 8; ++u) {
      int idx = tid + u * 256;
      int dk = idx >> 6, slot = idx & 63;
      int wjg = slot >> 3, wk = slot & 7;
      int j = wjg + 8 * wk;
      float v = 0.0f;
      if (wk < 5) {
        if (j < 32)       v = W_bc[(size_t)j * D_DIM + dc + dk];
        else if (j == 32) v = W_1[dc + dk];
      }
      wv[u] = v; widx[u] = dk * WST + slot;
    }
    __syncthreads();
#pragma unroll
    for (int q = 0; q < 4; ++q) {
      xs_t[(lhalf + q * 4 + 0) * XST + lrow] = xv[q].x;
      xs_t[(lhalf + q * 4 + 1) * XST + lrow] = xv[q].y;
      xs_t[(lhalf + q * 4 + 2) * XST + lrow] = xv[q].z;
      xs_t[(lhalf + q * 4 + 3) * XST + lrow] = xv[q].w;
    }
#pragma unroll
    for (int u = 0; u < 8; ++u) ws_t[widx[u]] = wv[u];
    __syncthreads();
#pragma unroll 8
    for (int dk = 0; dk < DK; ++dk) {
      float4 xr = *(const float4*)&xs_t[dk * XST + rg * 4];
      float4 wr = *(const float4*)&ws_t[dk * WST + jg * 8];
      float w4  = ws_t[dk * WST + jg * 8 + 4];
      float xa[4] = {xr.x, xr.y, xr.z, xr.w};
      float wa[5] = {wr.x, wr.y, wr.z, wr.w, w4};
#pragma unroll
      for (int i = 0; i < 4; ++i)
#pragma unroll
        for (int k = 0; k < 5; ++k)
          acc[i][k] = fmaf(xa[i], wa[k], acc[i][k]);
    }
  }

  float* pb = PBC + (size_t)ds * PROJ_ELEMS;
#pragma unroll
  for (int i = 0; i < 4; ++i) {
    int row = rb0 + rg * 4 + i;
#pragma unroll
    for (int k = 0; k < 5; ++k) {
      int j = jg + 8 * k;
      if (k < 4 || jg == 0) pb[(size_t)row * NJ + j] = acc[i][k];
    }
  }
}

__global__ __launch_bounds__(256) void k_proj_reduce(
    const float* __restrict__ PBC, const float* __restrict__ b_bc,
    const float* __restrict__ b_1, float* __restrict__ BC33) {
  const int idx = blockIdx.x * 256 + threadIdx.x;
  const int j = idx % NJ;
  float s = 0.0f;
#pragma unroll
  for (int k = 0; k < DSPLIT; ++k) s += PBC[(size_t)k * PROJ_ELEMS + idx];
  s += (j < 32) ? b_bc[j] : b_1[0];
  BC33[idx] = s;
}

// ---------------------------------------------------------------------------
// Pass 1: per-chunk local scan, h0 = 0. Emits chunk-end state H and delta-sum
// DS. Geometric-A fast path: dA_n = e1^(n+1), 1 exp + 15 muls per step.
// ---------------------------------------------------------------------------
template <int LC>
__global__ __launch_bounds__(256) void k_scan1(
    const float* __restrict__ x, const float* __restrict__ A_log,
    const float* __restrict__ W_d, const float* __restrict__ b_d,
    const float* __restrict__ BC33, float* __restrict__ DS,
    float* __restrict__ H, int NC) {
  const int cb = blockIdx.x % 3;
  const int c  = (blockIdx.x / 3) % NC;
  const int b  = blockIdx.x / (3 * NC);
  const int d  = cb * 256 + threadIdx.x;

  const float wd = W_d[d], bd = b_d[d];
  float Aln[N_ST];
  {
    const float4* al4 = (const float4*)(A_log + (size_t)d * N_ST);
#pragma unroll
    for (int q = 0; q < 4; ++q) {
      float4 v = al4[q];
      Aln[4*q+0] = -__expf(v.x) * 1.44269504088896f;
      Aln[4*q+1] = -__expf(v.y) * 1.44269504088896f;
      Aln[4*q+2] = -__expf(v.z) * 1.44269504088896f;
      Aln[4*q+3] = -__expf(v.w) * 1.44269504088896f;
    }
  }

  bool geom = true;
#pragma unroll
  for (int n = 1; n < N_ST; ++n) {
    float ref = (float)(n + 1) * Aln[0];
    geom = geom && (fabsf(Aln[n] - ref) <= 1e-4f * fabsf(ref) + 1e-12f);
  }
  const float a0 = Aln[0];

  float h[N_ST];
#pragma unroll
  for (int n = 0; n < N_ST; ++n) h[n] = 0.0f;
  float dsum = 0.0f;

  const int l0 = c * LC;
  const float* bc = BC33 + (size_t)(b * L_SEQ + l0) * NJ;
  const float* xp = x + (size_t)(b * L_SEQ + l0) * D_DIM + d;

  if (geom) {
#pragma unroll 8
    for (int l = 0; l < LC; ++l) {
      float s1 = bc[l * NJ + 32];
      float delta = softplus_f(fmaf(s1, wd, bd));
      float xv = xp[(size_t)l * D_DIM];
      float f = delta * xv;
      dsum += delta;
      float pw[N_ST];
      pow_tree(fast_exp2(a0 * delta), pw);
#pragma unroll
      for (int n = 0; n < N_ST; ++n)
        h[n] = fmaf(pw[n], h[n], f * bc[l * NJ + n]);
    }
  } else {
#pragma unroll 4
    for (int l = 0; l < LC; ++l) {
      float s1 = bc[l * NJ + 32];
      float delta = softplus_f(fmaf(s1, wd, bd));
      float xv = xp[(size_t)l * D_DIM];
      float f = delta * xv;
      dsum += delta;
#pragma unroll
      for (int n = 0; n < N_ST; ++n) {
        float dA = fast_exp2(delta * Aln[n]);
        h[n] = fmaf(dA, h[n], f * bc[l * NJ + n]);
      }
    }
  }

  DS[((size_t)b * NC + c) * D_DIM + d] = dsum;
  size_t base = ((size_t)(b * NC + c) * D_DIM + d) * N_ST;
  float4* H4 = (float4*)(H + base);
#pragma unroll
  for (int q = 0; q < 4; ++q)
    H4[q] = make_float4(h[4*q], h[4*q+1], h[4*q+2], h[4*q+3]);
}

// ---------------------------------------------------------------------------
// Pass 2: inter-chunk combine, in-place: H[c] becomes the INCOMING state.
// ---------------------------------------------------------------------------
__global__ __launch_bounds__(256) void k_combine(
    const float* __restrict__ A_log, const float* __restrict__ DS,
    float* __restrict__ H, int NC) {
  const int b  = blockIdx.x / 48;
  const int tl = (blockIdx.x % 48) * 256 + threadIdx.x;   // 0..12287
  const int d = tl >> 4, n = tl & 15;
  const float Aln = -__expf(A_log[d * N_ST + n]) * 1.44269504088896f;

  const float* dsp = DS + (size_t)b * NC * D_DIM + d;
  float* Hp = H + (size_t)b * NC * (D_DIM * N_ST) + tl;

  float h = 0.0f;
  float ds_c = dsp[0];
  float hold = Hp[0];
#pragma unroll 8
  for (int c = 0; c < NC; ++c) {
    float ds_n = 0.0f, hold_n = 0.0f;
    if (c + 1 < NC) {
      ds_n   = dsp[(size_t)(c + 1) * D_DIM];
      hold_n = Hp[(size_t)(c + 1) * (D_DIM * N_ST)];
    }
    float p = fast_exp2(Aln * ds_c);
    Hp[(size_t)c * (D_DIM * N_ST)] = h;
    h = fmaf(p, h, hold);
    ds_c = ds_n; hold = hold_n;
  }
}

// ---------------------------------------------------------------------------
// Pass 3: re-run the scan from the incoming state, emit y.
// ---------------------------------------------------------------------------
template <int LC>
__global__ __launch_bounds__(256) void k_scan2(
    const float* __restrict__ x, const float* __restrict__ A_log,
    const float* __restrict__ W_d, const float* __restrict__ b_d,
    const float* __restrict__ BC33, const float* __restrict__ HIN,
    float* __restrict__ out, int NC) {
  const int cb = blockIdx.x % 3;
  const int c  = (blockIdx.x / 3) % NC;
  const int b  = blockIdx.x / (3 * NC);
  const int d  = cb * 256 + threadIdx.x;

  const float wd = W_d[d], bd = b_d[d];
  float Aln[N_ST];
  {
    const float4* al4 = (const float4*)(A_log + (size_t)d * N_ST);
#pragma unroll
    for (int q = 0; q < 4; ++q) {
      float4 v = al4[q];
      Aln[4*q+0] = -__expf(v.x) * 1.44269504088896f;
      Aln[4*q+1] = -__expf(v.y) * 1.44269504088896f;
      Aln[4*q+2] = -__expf(v.z) * 1.44269504088896f;
      Aln[4*q+3] = -__expf(v.w) * 1.44269504088896f;
    }
  }

  bool geom = true;
#pragma unroll
  for (int n = 1; n < N_ST; ++n) {
    float ref = (float)(n + 1) * Aln[0];
    geom = geom && (fabsf(Aln[n] - ref) <= 1e-4f * fabsf(ref) + 1e-12f);
  }
  const float a0 = Aln[0];

  float h[N_ST];
  size_t base = ((size_t)(b * NC + c) * D_DIM + d) * N_ST;
  const float4* HIN4 = (const float4*)(HIN + base);
#pragma unroll
  for (int q = 0; q < 4; ++q) {
    float4 v = HIN4[q];
    h[4*q] = v.x; h[4*q+1] = v.y; h[4*q+2] = v.z; h[4*q+3] = v.w;
  }

  const int l0 = c * LC;
  const float* bc = BC33 + (size_t)(b * L_SEQ + l0) * NJ;
  const float* xp = x + (size_t)(b * L_SEQ + l0) * D_DIM + d;
  float* op = out + (size_t)(b * L_SEQ + l0) * D_DIM + d;

  if (geom) {
#pragma unroll 8
    for (int l = 0; l < LC; ++l) {
      float s1 = bc[l * NJ + 32];
      float delta = softplus_f(fmaf(s1, wd, bd));
      float xv = xp[(size_t)l * D_DIM];
      float f = delta * xv;
      float pw[N_ST];
      pow_tree(fast_exp2(a0 * delta), pw);
      float y = 0.0f;
#pragma unroll
      for (int n = 0; n < N_ST; ++n) {
        h[n] = fmaf(pw[n], h[n], f * bc[l * NJ + n]);
        y = fmaf(h[n], bc[l * NJ + 16 + n], y);
      }
      op[(size_t)l * D_DIM] = y;
    }
  } else {
#pragma unroll 4
    for (int l = 0; l < LC; ++l) {
      float s1 = bc[l * NJ + 32];
      float delta = softplus_f(fmaf(s1, wd, bd));
      float xv = xp[(size_t)l * D_DIM];
      float f = delta * xv;
      float y = 0.0f;
#pragma unroll
      for (int n = 0; n < N_ST; ++n) {
        float dA = fast_exp2(delta * Aln[n]);
        h[n] = fmaf(dA, h[n], f * bc[l * NJ + n]);
        y = fmaf(h[n], bc[l * NJ + 16 + n], y);
      }
      op[(size_t)l * D_DIM] = y;
    }
  }
}

// ---------------------------------------------------------------------------
extern "C" void kernel_launch(void* const* d_in, const int* in_sizes, int n_in,
                              void* d_out, int out_size, void* d_ws, size_t ws_size,
                              hipStream_t stream) {
  const float* x     = (const float*)d_in[0];
  const float* A_log = (const float*)d_in[1];
  const float* W_bc  = (const float*)d_in[2];
  const float* b_bc  = (const float*)d_in[3];
  const float* W_1   = (const float*)d_in[4];
  const float* b_1   = (const float*)d_in[5];
  const float* W_d   = (const float*)d_in[6];
  const float* b_d   = (const float*)d_in[7];
  float* out = (float*)d_out;
  float* ws  = (float*)d_ws;

  // NC=64: H traffic (write+combine r/w+read = 4x12.6 MB) vs NC=128's 100 MB,
  // while still giving 768 scan blocks = 3/CU. Fallbacks if ws is small.
  int NC = 8;
  const int cands[4] = {64, 32, 16, 8};
  for (int i = 0; i < 4; ++i) {
    size_t need = (9ull * PROJ_ELEMS + (3072ull + 49152ull) * cands[i]) * 4ull;
    if (ws_size >= need) { NC = cands[i]; break; }
  }

  float* BC33 = ws;
  float* PBC  = ws + PROJ_ELEMS;
  float* DSb  = PBC + (size_t)DSPLIT * PROJ_ELEMS;
  float* H    = DSb + (size_t)3072 * NC;

  k_proj_gemm<<<(NROWS / RB) * DSPLIT, 256, 0, stream>>>(x, W_bc, W_1, PBC);
  k_proj_reduce<<<PROJ_ELEMS / 256, 256, 0, stream>>>(PBC, b_bc, b_1, BC33);

  const int gs = 3 * NB * NC;
  switch (NC) {
    case 64:
      k_scan1<32><<<gs, 256, 0, stream>>>(x, A_log, W_d, b_d, BC33, DSb, H, NC);
      k_combine<<<192, 256, 0, stream>>>(A_log, DSb, H, NC);
      k_scan2<32><<<gs, 256, 0, stream>>>(x, A_log, W_d, b_d, BC33, H, out, NC);
      break;
    case 32:
      k_scan1<64><<<gs, 256, 0, stream>>>(x, A_log, W_d, b_d, BC33, DSb, H, NC);
      k_combine<<<192, 256, 0, stream>>>(A_log, DSb, H, NC);
      k_scan2<64><<<gs, 256, 0, stream>>>(x, A_log, W_d, b_d, BC33, H, out, NC);
      break;
    case 16:
      k_scan1<128><<<gs, 256, 0, stream>>>(x, A_log, W_d, b_d, BC33, DSb, H, NC);
      k_combine<<<192, 256, 0, stream>>>(A_log, DSb, H, NC);
      k_scan2<128><<<gs, 256, 0, stream>>>(x, A_log, W_d, b_d, BC33, H, out, NC);
      break;
    default:
      k_scan1<256><<<gs, 256, 0, stream>>>(x, A_log, W_d, b_d, BC33, DSb, H, NC);
      k_combine<<<192, 256, 0, stream>>>(A_log, DSb, H, NC);
      k_scan2<256><<<gs, 256, 0, stream>>>(x, A_log, W_d, b_d, BC33, H, out, NC);
      break;
  }
}